// Round 16
// baseline (122.223 us; speedup 1.0000x reference)
//
#include <hip/hip_runtime.h>
#include <math.h>

#define S_LEN 2048
#define DHEAD 128
#define NHEAD 16
#define QBLK  256                      // 8 waves x 2 interleaved 16-row M-tiles
#define KVBLK 64
#define ATT_SCALE 0.08838834764831845f // 1/sqrt(128)
#define LOG2E 1.4426950408889634f
#define SHIFT2 11.5f                   // fixed softmax shift in log2 units

#define KP 136                         // K tile pitch (bf16 elems)
#define VP 72                          // V^T tile pitch

typedef __attribute__((ext_vector_type(4))) float f32x4;
typedef __attribute__((ext_vector_type(8))) short s16x8;
typedef __attribute__((ext_vector_type(2))) int   i32x2;

// RNE f32 pair -> packed bf16 dword (T12 recipe; no builtin on gfx950)
__device__ __forceinline__ int pk2(float lo, float hi) {
  int d;
  asm("v_cvt_pk_bf16_f32 %0, %1, %2" : "=v"(d) : "v"(lo), "v"(hi));
  return d;
}

// LDS-only barrier: global prefetch loads stay in flight across it.
#define BARRIER() do {                                   \
    asm volatile("s_waitcnt lgkmcnt(0)" ::: "memory");   \
    __builtin_amdgcn_s_barrier();                        \
  } while (0)

// r16: (1) QUAD-buffered K/V -> ONE barrier per TWO kv-tiles (36 -> 18 syncs).
// Period for tiles (t0, t0+1): S(t0+2) L(t0+3) C(t0) S(t0+3) L(t0+4) C(t1)
// BARRIER. Writes hit bufs (t0+2)&3,(t0+3)&3; reads hit t0&3,(t0+1)&3 --
// disjoint mod 4 => race-free with a single barrier. Each LOAD is >= half a
// period (~2000cy) ahead of its STORE. LDS 140KB (1 block/CU as before).
// (2) INTERLEAVED M-tiles + per-M skip: wave w owns rows qb+16w and
// qb+128+16w, each independently active-tested -> on diagonal tiles all 8
// waves do ~half work each instead of 4 full + 4 idle (barrier-synced tile
// time ~halves there), and fully-masked M-tile computes vanish.
// pi(j) kv-slot permutation as r7 (P in registers, zero shuffles).

__global__ __launch_bounds__(512, 2)
void alibi_attn_fwd(const float* __restrict__ Qg, const float* __restrict__ Kg,
                    const float* __restrict__ Vg, float* __restrict__ Og)
{
  __shared__ __align__(16) short kt[4][KVBLK * KP];   // 69.6 KB
  __shared__ __align__(16) short vt[4][DHEAD * VP];   // 73.7 KB

  const int tid  = threadIdx.x;
  const int lane = tid & 63;
  const int w    = tid >> 6;      // wave 0..7
  const int l16  = lane & 15;
  const int lg   = lane >> 4;     // 0..3

  // n = p*64 + bh: XCD = n&7 = bh&7 (head-local L2). p in 0..3.
  const int n    = blockIdx.x;
  const int bh   = n & 63;
  const int p    = n >> 6;
  const int head = bh & (NHEAD - 1);

  const size_t base = (size_t)bh * S_LEN * DHEAD;
  const float* Q = Qg + base;
  const float* K = Kg + base;
  const float* V = Vg + base;
  float*       O = Og + base;

  const float slope2 = exp2f(-0.5f * (float)(head + 1)) * LOG2E;
  float cn16[4], rsv[4];
  #pragma unroll
  for (int x = 0; x < 4; ++x) { cn16[x] = (float)(16 * x) * slope2; rsv[x] = (float)x * slope2; }

  s16x8 ones;
  #pragma unroll
  for (int jj = 0; jj < 8; ++jj) ones[jj] = (short)0x3f80;  // bf16 1.0

  const f32x4 zero4 = {0.f, 0.f, 0.f, 0.f};

  const int qt0 = 7 - p, qt1 = p;
  const int qb0 = qt0 * QBLK, qb1 = qt1 * QBLK;
  const int n0  = 4 * (qt0 + 1);        // even -> phase boundary on period start
  const int NT  = n0 + 4 * (qt1 + 1);   // 36 for every block
  const int NP  = NT >> 1;              // 18 periods

  // ---- staging maps (512 threads, one tile shared by all 8 waves) ----
  const int kr  = tid >> 3;             // K row 0..63, d = d0k..d0k+15
  const int d0k = 16 * (tid & 7);
  const int grp = tid & 15, vnt = grp >> 2, vg = grp & 3;
  const int Rv  = 16 * vnt + 4 * vg;    // V rows Rv..Rv+3
  const int dv  = 4 * (tid >> 4);       // V d = dv..dv+3
  const int vslotb = 32 * (vnt >> 1) + 8 * vg + 4 * (vnt & 1);  // pi slot base

  f32x4 ka[4], va[4];   // prefetch regs: one tile in flight (32 VGPRs)

#define TKV(T) ((((T) < n0) ? (T) : (T) - n0) * KVBLK)

#define LOAD_TILE(KV0) do {                                            \
    const float* kp_ = K + (size_t)((KV0) + kr) * DHEAD + d0k;         \
    ka[0] = *(const f32x4*)(kp_);      ka[1] = *(const f32x4*)(kp_ + 4);  \
    ka[2] = *(const f32x4*)(kp_ + 8);  ka[3] = *(const f32x4*)(kp_ + 12); \
    const float* vp_ = V + (size_t)((KV0) + Rv) * DHEAD + dv;          \
    va[0] = *(const f32x4*)(vp_);                                      \
    va[1] = *(const f32x4*)(vp_ + DHEAD);                              \
    va[2] = *(const f32x4*)(vp_ + 2*DHEAD);                            \
    va[3] = *(const f32x4*)(vp_ + 3*DHEAD);                            \
  } while (0)

#define STORE_TILE(B) do {                                             \
    short* ktp = &kt[B][kr * KP + d0k];                                \
    union { int d[4]; s16x8 v; } u0, u1;                               \
    u0.d[0] = pk2(ka[0][0], ka[0][1]); u0.d[1] = pk2(ka[0][2], ka[0][3]); \
    u0.d[2] = pk2(ka[1][0], ka[1][1]); u0.d[3] = pk2(ka[1][2], ka[1][3]); \
    u1.d[0] = pk2(ka[2][0], ka[2][1]); u1.d[1] = pk2(ka[2][2], ka[2][3]); \
    u1.d[2] = pk2(ka[3][0], ka[3][1]); u1.d[3] = pk2(ka[3][2], ka[3][3]); \
    *(s16x8*)(ktp)     = u0.v;                                         \
    *(s16x8*)(ktp + 8) = u1.v;                                         \
    _Pragma("unroll")                                                  \
    for (int e = 0; e < 4; ++e) {                                      \
      i32x2 dvv;                                                       \
      dvv[0] = pk2(va[0][e], va[1][e]);                                \
      dvv[1] = pk2(va[2][e], va[3][e]);                                \
      *(i32x2*)&vt[B][(dv + e) * VP + vslotb] = dvv;                   \
    }                                                                  \
  } while (0)

  // ---- per-phase state: M-tile m of wave w = rows qb + 16*(w + 8m) ----
  s16x8 qf[2][4];
  f32x4 oacc[2][8], lacc[2];
  int   rowb[2];   // absolute first row of each M-tile

  auto init_phase = [&](int qbn) {
    #pragma unroll
    for (int m = 0; m < 2; ++m) {
      rowb[m] = qbn + 16 * (w + 8 * m);
      const float* qp = Q + (size_t)(rowb[m] + l16) * DHEAD + 8*lg;
      #pragma unroll
      for (int c = 0; c < 4; ++c) {
        f32x4 a = *(const f32x4*)(qp + 32*c);
        f32x4 b = *(const f32x4*)(qp + 32*c + 4);
        const float sc = ATT_SCALE * LOG2E;
        union { int d[4]; s16x8 v; } uu;
        uu.d[0] = pk2(a[0]*sc, a[1]*sc); uu.d[1] = pk2(a[2]*sc, a[3]*sc);
        uu.d[2] = pk2(b[0]*sc, b[1]*sc); uu.d[3] = pk2(b[2]*sc, b[3]*sc);
        qf[m][c] = uu.v;
      }
      #pragma unroll
      for (int dt = 0; dt < 8; ++dt) oacc[m][dt] = zero4;
      lacc[m] = zero4;
    }
  };

  auto epilogue = [&]() {
    #pragma unroll
    for (int m = 0; m < 2; ++m) {
      #pragma unroll
      for (int r = 0; r < 4; ++r) {
        const float inv = 1.0f / lacc[m][r];
        float* op = O + (size_t)(rowb[m] + 4*lg + r) * DHEAD + l16;
        #pragma unroll
        for (int dt = 0; dt < 8; ++dt) op[dt * 16] = oacc[m][dt][r] * inv;
      }
    }
  };

  auto compute = [&](int t) {
    const int kv0 = TKV(t);
    const bool act0 = (kv0 <= rowb[0] + 15);   // per-M-tile activity
    const bool act1 = (kv0 <= rowb[1] + 15);
    if (!(act0 || act1)) return;
    const short* ktc = kt[t & 3];
    const short* vtc = vt[t & 3];

    // ---- QK^T swapped: sacc = K * Q^T -> q-row = l16, kv in-register ----
    f32x4 sacc[2][4];
    #pragma unroll
    for (int nt = 0; nt < 4; ++nt) { sacc[0][nt] = zero4; sacc[1][nt] = zero4; }
    __builtin_amdgcn_s_setprio(1);
    #pragma unroll
    for (int c = 0; c < 4; ++c) {
      #pragma unroll
      for (int nt = 0; nt < 4; ++nt) {
        s16x8 kf = *(const s16x8*)&ktc[(nt*16 + l16) * KP + 32*c + 8*lg];
        if (act0) sacc[0][nt] = __builtin_amdgcn_mfma_f32_16x16x32_bf16(kf, qf[0][c], sacc[0][nt], 0, 0, 0);
        if (act1) sacc[1][nt] = __builtin_amdgcn_mfma_f32_16x16x32_bf16(kf, qf[1][c], sacc[1][nt], 0, 0, 0);
      }
    }
    __builtin_amdgcn_s_setprio(0);

    // ---- softmax in-register: p = 2^(s + (j-i)*slope2 - SHIFT2) ----
    s16x8 pa[2][2];
    #pragma unroll
    for (int m = 0; m < 2; ++m) {
      const bool actm = m ? act1 : act0;
      if (!actm) continue;
      const int dji = kv0 + 4*lg - (rowb[m] + l16);   // j - i at (nt=0, r=0)
      const bool needMask = (kv0 + KVBLK - 1 > rowb[m]);
      const float b0m = (float)dji * slope2 - SHIFT2;
      float pv[4][4];
      #pragma unroll
      for (int nt = 0; nt < 4; ++nt) {
        const float bmn = b0m + cn16[nt];
        #pragma unroll
        for (int r = 0; r < 4; ++r)
          pv[nt][r] = __builtin_amdgcn_exp2f(sacc[m][nt][r] + bmn + rsv[r]);
      }
      if (needMask) {
        #pragma unroll
        for (int nt = 0; nt < 4; ++nt)
          #pragma unroll
          for (int r = 0; r < 4; ++r)
            if (dji + 16*nt + r > 0) pv[nt][r] = 0.f;
      }
      #pragma unroll
      for (int c2 = 0; c2 < 2; ++c2) {
        union { int d[4]; s16x8 v; } uu;
        uu.d[0] = pk2(pv[2*c2][0],   pv[2*c2][1]);
        uu.d[1] = pk2(pv[2*c2][2],   pv[2*c2][3]);
        uu.d[2] = pk2(pv[2*c2+1][0], pv[2*c2+1][1]);
        uu.d[3] = pk2(pv[2*c2+1][2], pv[2*c2+1][3]);
        pa[m][c2] = uu.v;   // k-slots c2*32 + 8*lg .. +7 in pi space
      }
    }

    // ---- PV in pi space; row-sum via ones-MFMA ----
    __builtin_amdgcn_s_setprio(1);
    #pragma unroll
    for (int c2 = 0; c2 < 2; ++c2) {
      if (act0) lacc[0] = __builtin_amdgcn_mfma_f32_16x16x32_bf16(pa[0][c2], ones, lacc[0], 0, 0, 0);
      if (act1) lacc[1] = __builtin_amdgcn_mfma_f32_16x16x32_bf16(pa[1][c2], ones, lacc[1], 0, 0, 0);
      #pragma unroll
      for (int dt = 0; dt < 8; ++dt) {
        s16x8 bv = *(const s16x8*)&vtc[(dt*16 + l16) * VP + c2*32 + 8*lg];
        if (act0) oacc[0][dt] = __builtin_amdgcn_mfma_f32_16x16x32_bf16(pa[0][c2], bv, oacc[0][dt], 0, 0, 0);
        if (act1) oacc[1][dt] = __builtin_amdgcn_mfma_f32_16x16x32_bf16(pa[1][c2], bv, oacc[1][dt], 0, 0, 0);
      }
    }
    __builtin_amdgcn_s_setprio(0);
  };

  // ---- prologue: stage tiles 0,1; tile 2 in regs ----
  init_phase(qb0);
  LOAD_TILE(TKV(0));  STORE_TILE(0);
  LOAD_TILE(TKV(1));  STORE_TILE(1);
  LOAD_TILE(TKV(2));                    // NT >= 20 in phase 0, always valid
  __syncthreads();

  for (int per = 0; per < NP; ++per) {
    const int t0 = 2 * per, t1 = t0 + 1;
    if (t0 == n0) { epilogue(); init_phase(qb1); }   // n0 even -> period start

    if (t0 + 2 < NT) STORE_TILE((t0 + 2) & 3);
    if (t0 + 3 < NT) LOAD_TILE(TKV(t0 + 3));
    compute(t0);
    if (t0 + 3 < NT) STORE_TILE((t0 + 3) & 3);
    if (t0 + 4 < NT) LOAD_TILE(TKV(t0 + 4));
    compute(t1);

    BARRIER();   // one lgkm-only barrier per TWO tiles
  }
  epilogue();
}

extern "C" void kernel_launch(void* const* d_in, const int* in_sizes, int n_in,
                              void* d_out, int out_size, void* d_ws, size_t ws_size,
                              hipStream_t stream) {
  (void)in_sizes; (void)n_in; (void)out_size; (void)d_ws; (void)ws_size;
  const float* q = (const float*)d_in[0];
  const float* k = (const float*)d_in[1];
  const float* v = (const float*)d_in[2];
  float* o = (float*)d_out;
  dim3 grid(256);    // 64 heads x 4 uniform q-tile pairs; exactly 1 block/CU
  dim3 block(512);
  alibi_attn_fwd<<<grid, block, 0, stream>>>(q, k, v, o);
}

// Round 17
// 105.643 us; speedup vs baseline: 1.1569x; 1.1569x over previous
//
#include <hip/hip_runtime.h>
#include <math.h>

#define S_LEN 2048
#define DHEAD 128
#define NHEAD 16
#define QBLK  256                      // 8 waves x 32 q-rows (two 16-row M-tiles)
#define KVBLK 64
#define ATT_SCALE 0.08838834764831845f // 1/sqrt(128)
#define LOG2E 1.4426950408889634f
#define SHIFT2 11.5f                   // fixed softmax shift in log2 units

#define KP 136                         // K tile pitch (bf16 elems)
#define VP 72                          // V^T tile pitch

typedef __attribute__((ext_vector_type(4))) float f32x4;
typedef __attribute__((ext_vector_type(8))) short s16x8;
typedef __attribute__((ext_vector_type(2))) int   i32x2;

// RNE f32 pair -> packed bf16 dword (T12 recipe; no builtin on gfx950)
__device__ __forceinline__ int pk2(float lo, float hi) {
  int d;
  asm("v_cvt_pk_bf16_f32 %0, %1, %2" : "=v"(d) : "v"(lo), "v"(hi));
  return d;
}

// === r17: verbatim restore of r11 (best measured: 106.4 us clean) ===
// r12-r16 isolated and nulled/regressed six structural levers on this base:
// lgkm-only barrier, store-reorder, deferred-PV (T15), A/B wave role-split
// (T5 mechanism), barrier-halving via quad-buffer, diagonal M-interleave.
// Structure: one 8-wave block per CU (512 thr); all 8 waves share one staged
// K/V tile (halves staging vs 2x4-wave blocks); grid 256 = 1 block/CU;
// q-tile pairing {7-p, p} -> every block exactly 36 kv-tiles (zero tail);
// LDS double-buffer 71.7KB, 1 barrier/tile; swapped QK^T -> in-register
// softmax (fixed shift, exp2 domain) -> P packed in regs via v_cvt_pk_bf16
// -> PV through pi-permuted V^T slots (permutation cancels in the dot
// product; zero cross-lane shuffles). Occupancy is register-pinned at
// 2 waves/SIMD (unified VGPR+AGPR ~230; r9/r14 proved both directions).

__global__ __launch_bounds__(512, 2)
void alibi_attn_fwd(const float* __restrict__ Qg, const float* __restrict__ Kg,
                    const float* __restrict__ Vg, float* __restrict__ Og)
{
  __shared__ __align__(16) short kt[2][KVBLK * KP];   // K tiles [buf][kv][d]
  __shared__ __align__(16) short vt[2][DHEAD * VP];   // V^T tiles [buf][d][pi(kv)]

  const int tid  = threadIdx.x;
  const int lane = tid & 63;
  const int w    = tid >> 6;      // wave 0..7, owns 32 q-rows per phase
  const int l16  = lane & 15;
  const int lg   = lane >> 4;     // 0..3

  // n = p*64 + bh: XCD = n&7 = bh&7 (head-local L2). p in 0..3.
  const int n    = blockIdx.x;
  const int bh   = n & 63;
  const int p    = n >> 6;
  const int head = bh & (NHEAD - 1);

  const size_t base = (size_t)bh * S_LEN * DHEAD;
  const float* Q = Qg + base;
  const float* K = Kg + base;
  const float* V = Vg + base;
  float*       O = Og + base;

  const float slope2 = exp2f(-0.5f * (float)(head + 1)) * LOG2E;
  float cn16[4], rsv[4];
  #pragma unroll
  for (int x = 0; x < 4; ++x) { cn16[x] = (float)(16 * x) * slope2; rsv[x] = (float)x * slope2; }

  s16x8 ones;
  #pragma unroll
  for (int jj = 0; jj < 8; ++jj) ones[jj] = (short)0x3f80;  // bf16 1.0

  const f32x4 zero4 = {0.f, 0.f, 0.f, 0.f};

  const int qt0 = 7 - p, qt1 = p;
  const int qb0 = qt0 * QBLK, qb1 = qt1 * QBLK;
  const int n0  = 4 * (qt0 + 1);
  const int NT  = n0 + 4 * (qt1 + 1);   // 36 for every block

  // ---- staging maps (512 threads, one tile shared by all 8 waves) ----
  const int kr  = tid >> 3;             // K row 0..63, d = d0k..d0k+15
  const int d0k = 16 * (tid & 7);
  const int grp = tid & 15, vnt = grp >> 2, vg = grp & 3;
  const int Rv  = 16 * vnt + 4 * vg;    // V rows Rv..Rv+3
  const int dv  = 4 * (tid >> 4);       // V d = dv..dv+3
  const int vslotb = 32 * (vnt >> 1) + 8 * vg + 4 * (vnt & 1);  // pi slot base

  f32x4 ka[4], va[4];   // prefetch regs: one tile in flight (32 VGPRs)

#define LOAD_TILE(KV0) do {                                            \
    const float* kp_ = K + (size_t)((KV0) + kr) * DHEAD + d0k;         \
    ka[0] = *(const f32x4*)(kp_);      ka[1] = *(const f32x4*)(kp_ + 4);  \
    ka[2] = *(const f32x4*)(kp_ + 8);  ka[3] = *(const f32x4*)(kp_ + 12); \
    const float* vp_ = V + (size_t)((KV0) + Rv) * DHEAD + dv;          \
    va[0] = *(const f32x4*)(vp_);                                      \
    va[1] = *(const f32x4*)(vp_ + DHEAD);                              \
    va[2] = *(const f32x4*)(vp_ + 2*DHEAD);                            \
    va[3] = *(const f32x4*)(vp_ + 3*DHEAD);                            \
  } while (0)

#define STORE_TILE(B) do {                                             \
    short* ktp = &kt[B][kr * KP + d0k];                                \
    union { int d[4]; s16x8 v; } u0, u1;                               \
    u0.d[0] = pk2(ka[0][0], ka[0][1]); u0.d[1] = pk2(ka[0][2], ka[0][3]); \
    u0.d[2] = pk2(ka[1][0], ka[1][1]); u0.d[3] = pk2(ka[1][2], ka[1][3]); \
    u1.d[0] = pk2(ka[2][0], ka[2][1]); u1.d[1] = pk2(ka[2][2], ka[2][3]); \
    u1.d[2] = pk2(ka[3][0], ka[3][1]); u1.d[3] = pk2(ka[3][2], ka[3][3]); \
    *(s16x8*)(ktp)     = u0.v;                                         \
    *(s16x8*)(ktp + 8) = u1.v;                                         \
    _Pragma("unroll")                                                  \
    for (int e = 0; e < 4; ++e) {                                      \
      i32x2 dvv;                                                       \
      dvv[0] = pk2(va[0][e], va[1][e]);                                \
      dvv[1] = pk2(va[2][e], va[3][e]);                                \
      *(i32x2*)&vt[B][(dv + e) * VP + vslotb] = dvv;                   \
    }                                                                  \
  } while (0)

  // ---- per-phase state ----
  s16x8 qf[2][4];
  f32x4 oacc[2][8], lacc[2];
  int   iq0 = 0;
  int   qb  = qb0;

  auto init_phase = [&](int qbn) {
    qb  = qbn;
    iq0 = qbn + 32 * w + l16;
    #pragma unroll
    for (int m = 0; m < 2; ++m) {
      const float* qp = Q + (size_t)(qbn + 32*w + 16*m + l16) * DHEAD + 8*lg;
      #pragma unroll
      for (int c = 0; c < 4; ++c) {
        f32x4 a = *(const f32x4*)(qp + 32*c);
        f32x4 b = *(const f32x4*)(qp + 32*c + 4);
        const float sc = ATT_SCALE * LOG2E;
        union { int d[4]; s16x8 v; } uu;
        uu.d[0] = pk2(a[0]*sc, a[1]*sc); uu.d[1] = pk2(a[2]*sc, a[3]*sc);
        uu.d[2] = pk2(b[0]*sc, b[1]*sc); uu.d[3] = pk2(b[2]*sc, b[3]*sc);
        qf[m][c] = uu.v;
      }
      #pragma unroll
      for (int dt = 0; dt < 8; ++dt) oacc[m][dt] = zero4;
      lacc[m] = zero4;
    }
  };

  auto epilogue = [&](int qbn) {
    #pragma unroll
    for (int m = 0; m < 2; ++m) {
      #pragma unroll
      for (int r = 0; r < 4; ++r) {
        const float inv = 1.0f / lacc[m][r];
        float* op = O + (size_t)(qbn + 32*w + 16*m + 4*lg + r) * DHEAD + l16;
        #pragma unroll
        for (int dt = 0; dt < 8; ++dt) op[dt * 16] = oacc[m][dt][r] * inv;
      }
    }
  };

  init_phase(qb0);
  LOAD_TILE(0);
  STORE_TILE(0);
  LOAD_TILE(KVBLK);          // tile 1 (n0 >= 20, always in phase 0)
  __syncthreads();

  for (int s = 0; s < NT; ++s) {
    if (s == n0) { epilogue(qb0); init_phase(qb1); }
    const int cur = s & 1;
    if (s + 1 < NT) STORE_TILE((s + 1) & 1);   // other buffer; loads drained at prev barrier
    if (s + 2 < NT) {
      const int s2 = s + 2;
      LOAD_TILE(((s2 < n0) ? s2 : s2 - n0) * KVBLK);
    }
    const int kv0 = ((s < n0) ? s : s - n0) * KVBLK;

    if (kv0 <= qb + 32 * w + 31) {
      const short* ktc = kt[cur];
      const short* vtc = vt[cur];

      // ---- QK^T swapped: sacc = K * Q^T -> q-row = l16, kv in-register ----
      f32x4 sacc[2][4];
      #pragma unroll
      for (int nt = 0; nt < 4; ++nt) { sacc[0][nt] = zero4; sacc[1][nt] = zero4; }
      __builtin_amdgcn_s_setprio(1);
      #pragma unroll
      for (int c = 0; c < 4; ++c) {
        #pragma unroll
        for (int nt = 0; nt < 4; ++nt) {
          s16x8 kf = *(const s16x8*)&ktc[(nt*16 + l16) * KP + 32*c + 8*lg];
          sacc[0][nt] = __builtin_amdgcn_mfma_f32_16x16x32_bf16(kf, qf[0][c], sacc[0][nt], 0, 0, 0);
          sacc[1][nt] = __builtin_amdgcn_mfma_f32_16x16x32_bf16(kf, qf[1][c], sacc[1][nt], 0, 0, 0);
        }
      }
      __builtin_amdgcn_s_setprio(0);

      // ---- softmax in-register: p = 2^(s + (j-i)*slope2 - SHIFT2) ----
      const bool needMask = (kv0 + KVBLK - 1 > qb + 32 * w);  // diagonal tiles only
      s16x8 pa[2][2];
      #pragma unroll
      for (int m = 0; m < 2; ++m) {
        const int dji = kv0 + 4*lg - (iq0 + 16*m);   // j - i at (nt=0, r=0)
        const float b0m = (float)dji * slope2 - SHIFT2;
        float pv[4][4];
        #pragma unroll
        for (int nt = 0; nt < 4; ++nt) {
          const float bmn = b0m + cn16[nt];
          #pragma unroll
          for (int r = 0; r < 4; ++r)
            pv[nt][r] = __builtin_amdgcn_exp2f(sacc[m][nt][r] + bmn + rsv[r]);
        }
        if (needMask) {
          #pragma unroll
          for (int nt = 0; nt < 4; ++nt)
            #pragma unroll
            for (int r = 0; r < 4; ++r)
              if (dji + 16*nt + r > 0) pv[nt][r] = 0.f;
        }
        #pragma unroll
        for (int c2 = 0; c2 < 2; ++c2) {
          union { int d[4]; s16x8 v; } uu;
          uu.d[0] = pk2(pv[2*c2][0],   pv[2*c2][1]);
          uu.d[1] = pk2(pv[2*c2][2],   pv[2*c2][3]);
          uu.d[2] = pk2(pv[2*c2+1][0], pv[2*c2+1][1]);
          uu.d[3] = pk2(pv[2*c2+1][2], pv[2*c2+1][3]);
          pa[m][c2] = uu.v;   // k-slots c2*32 + 8*lg .. +7 in pi space
        }
      }

      // ---- PV in pi space; row-sum via ones-MFMA; bv reused by both M-tiles ----
      __builtin_amdgcn_s_setprio(1);
      #pragma unroll
      for (int c2 = 0; c2 < 2; ++c2) {
        lacc[0] = __builtin_amdgcn_mfma_f32_16x16x32_bf16(pa[0][c2], ones, lacc[0], 0, 0, 0);
        lacc[1] = __builtin_amdgcn_mfma_f32_16x16x32_bf16(pa[1][c2], ones, lacc[1], 0, 0, 0);
        #pragma unroll
        for (int dt = 0; dt < 8; ++dt) {
          s16x8 bv = *(const s16x8*)&vtc[(dt*16 + l16) * VP + c2*32 + 8*lg];
          oacc[0][dt] = __builtin_amdgcn_mfma_f32_16x16x32_bf16(pa[0][c2], bv, oacc[0][dt], 0, 0, 0);
          oacc[1][dt] = __builtin_amdgcn_mfma_f32_16x16x32_bf16(pa[1][c2], bv, oacc[1][dt], 0, 0, 0);
        }
      }
      __builtin_amdgcn_s_setprio(0);
    }
    __syncthreads();
  }
  epilogue(qb1);
}

extern "C" void kernel_launch(void* const* d_in, const int* in_sizes, int n_in,
                              void* d_out, int out_size, void* d_ws, size_t ws_size,
                              hipStream_t stream) {
  (void)in_sizes; (void)n_in; (void)out_size; (void)d_ws; (void)ws_size;
  const float* q = (const float*)d_in[0];
  const float* k = (const float*)d_in[1];
  const float* v = (const float*)d_in[2];
  float* o = (float*)d_out;
  dim3 grid(256);    // 64 heads x 4 uniform q-tile pairs; exactly 1 block/CU
  dim3 block(512);
  alibi_attn_fwd<<<grid, block, 0, stream>>>(q, k, v, o);
}